// Round 3
// baseline (1676.171 us; speedup 1.0000x reference)
//
#include <hip/hip_runtime.h>

typedef unsigned short u16;
typedef __bf16 v8bf __attribute__((ext_vector_type(8)));
typedef unsigned short v8u __attribute__((ext_vector_type(8)));
typedef float f32x4 __attribute__((ext_vector_type(4)));

static constexpr int DIMC = 768;
static constexpr int HEADS = 12;
static constexpr int WINS  = 14;
static constexpr int ACCH  = 192;   // adapter channels
static constexpr int NTOK  = 196;   // 14*14
static constexpr int MW    = 24500; // 125 windows * 196 tokens
static constexpr int MWP   = 24576; // padded to tile multiple
static constexpr int MS    = 20480; // 5*64*64 spatial tokens

__device__ __forceinline__ float bf2f(u16 u) {
  union { unsigned int i; float f; } x; x.i = ((unsigned int)u) << 16; return x.f;
}
__device__ __forceinline__ u16 f2bf(float f) {
  union { float f; unsigned int i; } x; x.f = f;
  unsigned int r = x.i + 0x7fffu + ((x.i >> 16) & 1u);
  return (u16)(r >> 16);
}
__device__ __forceinline__ float gelu_f(float x) {
  return 0.5f * x * (1.0f + erff(x * 0.70710678118654752440f));
}
// async global->LDS, 16B per lane. LDS dest is wave-uniform base + lane*16.
__device__ __forceinline__ void cp16(const u16* g, u16* l) {
  __builtin_amdgcn_global_load_lds(
      (const __attribute__((address_space(1))) unsigned int*)(const void*)g,
      (__attribute__((address_space(3))) unsigned int*)(void*)l, 16, 0, 0);
}

// ---------------- weight prep ----------------
__global__ void k_zero16(u16* p, int n) {
  int i = blockIdx.x * 256 + threadIdx.x;
  if (i < n) p[i] = 0;
}
// U[k][b] = sum_a facu_W[a][k] * fac_W[b][a]   (fac = qfac or vfac)
__global__ void k_compute_U(const float* __restrict__ facu, const float* __restrict__ qfac,
                            const float* __restrict__ vfac, float* __restrict__ Uq,
                            float* __restrict__ Uv) {
  int idx = blockIdx.x * 256 + threadIdx.x;
  if (idx >= 2 * 768 * 32) return;
  const int which = idx / (768 * 32);
  const int rem = idx - which * 768 * 32;
  const int k = rem >> 5, b = rem & 31;
  const float* fac = which ? vfac : qfac;
  float s = 0.f;
  for (int a = 0; a < 32; ++a) s += facu[a * 768 + k] * fac[b * 32 + a];
  (which ? Uv : Uq)[rem] = s;
}
// Wc[n][k] = qkv_W[n][k] (+ sum_b U{q,v}[k][b]*facv_W[n'][b] for q/v blocks), cast bf16
__global__ void k_build_wcomb(const float* __restrict__ qkvW, const float* __restrict__ Uq,
                              const float* __restrict__ Uv, const float* __restrict__ facv,
                              u16* __restrict__ Wc) {
  int idx = blockIdx.x * 256 + threadIdx.x;
  if (idx >= 2304 * 768) return;
  const int n = idx / 768, k = idx - n * 768;
  float v = qkvW[idx];
  if (n < 768) {
    float s = 0.f;
    for (int b = 0; b < 32; ++b) s += Uq[k * 32 + b] * facv[n * 32 + b];
    v += s;
  } else if (n >= 1536) {
    const int nn = n - 1536;
    float s = 0.f;
    for (int b = 0; b < 32; ++b) s += Uv[k * 32 + b] * facv[nn * 32 + b];
    v += s;
  }
  Wc[idx] = f2bf(v);
}
__global__ void k_cast_pad(const float* __restrict__ src, u16* __restrict__ dst,
                           int rows, int cols, int rowsPad) {
  int idx = blockIdx.x * 256 + threadIdx.x;
  if (idx >= rowsPad * cols) return;
  const int r = idx / cols;
  dst[idx] = (r < rows) ? f2bf(src[idx]) : (u16)0;
}
// ac_W [192][192][3][3][3] -> Wconv [256 pad][27*192] with k = tap*192+ci
__global__ void k_conv_repack(const float* __restrict__ src, u16* __restrict__ dst) {
  int idx = blockIdx.x * 256 + threadIdx.x;
  if (idx >= 256 * 5184) return;
  const int co = idx / 5184;
  const int rem = idx - co * 5184;
  const int tap = rem / 192, ci = rem - tap * 192;
  dst[idx] = (co < 192) ? f2bf(src[co * 5184 + ci * 27 + tap]) : (u16)0;
}

// ---------------- LayerNorm (optionally fused window-partition) ----------------
template<bool WINDOWED>
__global__ __launch_bounds__(256)
void ln_k(const float* __restrict__ X, const float* __restrict__ w,
          const float* __restrict__ b, u16* __restrict__ out) {
  const int r = (int)blockIdx.x;
  const int t = (int)threadIdx.x;
  int src = r;
  bool zero = false;
  if (WINDOWED) {
    if (r >= MW) zero = true;
    else {
      const int win = r / NTOK, tk = r - win * NTOK;
      const int img = win / 25, wrem = win - img * 25, wy = wrem / 5, wx = wrem - wy * 5;
      const int ty = tk / WINS, tx = tk - ty * WINS;
      const int y = wy * WINS + ty, x = wx * WINS + tx;
      if (y >= 64 || x >= 64) zero = true;
      else src = (img << 12) + (y << 6) + x;
    }
  }
  u16* orow = out + (size_t)r * DIMC;
  if (zero) {
    for (int c = t; c < DIMC; c += 256) orow[c] = 0;
    return;
  }
  const float* xr = X + (size_t)src * DIMC;
  const float v0 = xr[t], v1 = xr[t + 256], v2 = xr[t + 512];
  float s = v0 + v1 + v2, ss = v0 * v0 + v1 * v1 + v2 * v2;
#pragma unroll
  for (int o = 32; o > 0; o >>= 1) { s += __shfl_xor(s, o, 64); ss += __shfl_xor(ss, o, 64); }
  __shared__ float red[8];
  const int wave = t >> 6, lane = t & 63;
  if (lane == 0) { red[wave] = s; red[4 + wave] = ss; }
  __syncthreads();
  s = red[0] + red[1] + red[2] + red[3];
  ss = red[4] + red[5] + red[6] + red[7];
  const float mean = s * (1.0f / 768.0f);
  const float var = ss * (1.0f / 768.0f) - mean * mean;
  const float rstd = rsqrtf(var + 1e-5f);
  orow[t]       = f2bf((v0 - mean) * rstd * w[t]       + b[t]);
  orow[t + 256] = f2bf((v1 - mean) * rstd * w[t + 256] + b[t + 256]);
  orow[t + 512] = f2bf((v2 - mean) * rstd * w[t + 512] + b[t + 512]);
}

// ---------------- GEMM: C[M,N] = A[M,K] @ B[N,K]^T (+bias, epilogues) ----------------
// EPI: 0 = f32 out (bias); 1 = bf16 out (bias); 2 = bf16 out (bias+GELU);
//      3 = f32 out (bias+residual); 4 = bf16 qkv-scatter per (win,head);
//      5 = f32 window-unpartition + in-place residual add
// CONV: A rows gathered as 3x3x3 SAME conv over [5][64][64][192]; K = tap*192+ci
template<int EPI, bool CONV>
__global__ __launch_bounds__(256)
void gemm_bt(const u16* __restrict__ A, const u16* __restrict__ B,
             const float* __restrict__ bias, const float* __restrict__ resid,
             float* __restrict__ outF, u16* __restrict__ outB,
             int M, int N, int K, const u16* __restrict__ zrow) {
  __shared__ u16 At[128 * 64];
  __shared__ u16 Bt[128 * 64];
  const int bm = (int)blockIdx.y, bn = (int)blockIdx.x;
  const int t = (int)threadIdx.x;
  const int wave = t >> 6, lane = t & 63;
  const int wm = wave >> 1, wn = wave & 1;
  const int lrow = lane >> 3;                // 0..7 (row within 8-row group)
  const int c16s = (lane & 7) ^ lrow;        // pre-swizzled source col16
  const int li = lane & 15, lq = lane >> 4;

  f32x4 acc[4][4];
  const f32x4 vzero = {0.f, 0.f, 0.f, 0.f};
#pragma unroll
  for (int a = 0; a < 4; ++a)
#pragma unroll
    for (int b = 0; b < 4; ++b) acc[a][b] = vzero;

  const int nk = K >> 6;
  for (int kt = 0; kt < nk; ++kt) {
    int cD = 0, cY = 0, cX = 0, cblk = 0;
    if (CONV) {
      const int tap = kt / 3;
      cblk = (kt - tap * 3) << 6;
      const int kd = tap / 9, r9 = tap - kd * 9, ky = r9 / 3;
      cD = kd - 1; cY = ky - 1; cX = (r9 - ky * 3) - 1;
    }
#pragma unroll
    for (int i = 0; i < 4; ++i) {           // stage A: 128x64 bf16
      const int r0 = i * 32 + wave * 8;
      const int grow = bm * 128 + r0 + lrow;
      const u16* src;
      if (CONV) {
        const int d = (grow >> 12) + cD, y = ((grow >> 6) & 63) + cY, x = (grow & 63) + cX;
        if ((unsigned)d < 5u && (unsigned)y < 64u && (unsigned)x < 64u)
          src = A + (size_t)((d << 12) + (y << 6) + x) * ACCH + cblk + c16s * 8;
        else
          src = zrow + c16s * 8;
      } else {
        src = A + (size_t)grow * K + (kt << 6) + c16s * 8;
      }
      cp16(src, &At[r0 * 64]);
    }
#pragma unroll
    for (int i = 0; i < 4; ++i) {           // stage B: 128x64 bf16
      const int r0 = i * 32 + wave * 8;
      const int grow = bn * 128 + r0 + lrow;
      cp16(B + (size_t)grow * K + (kt << 6) + c16s * 8, &Bt[r0 * 64]);
    }
    __syncthreads();                         // drains vmcnt for global_load_lds
#pragma unroll
    for (int kk = 0; kk < 2; ++kk) {
      v8bf af[4], bg[4];
#pragma unroll
      for (int mf = 0; mf < 4; ++mf) {
        const int row = wm * 64 + mf * 16 + li;
        const int c16 = (kk * 4 + lq) ^ (li & 7);
        af[mf] = *(const v8bf*)&At[row * 64 + c16 * 8];
      }
#pragma unroll
      for (int nf = 0; nf < 4; ++nf) {
        const int row = wn * 64 + nf * 16 + li;
        const int c16 = (kk * 4 + lq) ^ (li & 7);
        bg[nf] = *(const v8bf*)&Bt[row * 64 + c16 * 8];
      }
#pragma unroll
      for (int mf = 0; mf < 4; ++mf)
#pragma unroll
        for (int nf = 0; nf < 4; ++nf)
          acc[mf][nf] = __builtin_amdgcn_mfma_f32_16x16x32_bf16(af[mf], bg[nf], acc[mf][nf], 0, 0, 0);
    }
    __syncthreads();
  }

#pragma unroll
  for (int mf = 0; mf < 4; ++mf) {
#pragma unroll
    for (int nf = 0; nf < 4; ++nf) {
      const int gc = bn * 128 + wn * 64 + nf * 16 + li;
#pragma unroll
      for (int r = 0; r < 4; ++r) {
        const int gr = bm * 128 + wm * 64 + mf * 16 + lq * 4 + r;
        if (gr < M && gc < N) {
          float v = acc[mf][nf][r] + bias[gc];
          if (EPI == 2) v = gelu_f(v);
          if (EPI == 3) v += resid[(size_t)gr * N + gc];
          if (EPI == 0 || EPI == 3) {
            outF[(size_t)gr * N + gc] = v;
          } else if (EPI == 4) {
            // scatter qkv into per-(win,head) contiguous [Q|K|V][196][64]
            const int sec = gc / 768;
            const int hm = gc - sec * 768;
            const int hd = hm >> 6, dd = hm & 63;
            const int win = gr / 196, tk = gr - win * 196;
            outB[(size_t)(((win * HEADS + hd) * 3 + sec) * NTOK + tk) * 64 + dd] = f2bf(v);
          } else if (EPI == 5) {
            // window-unpartition + in-place residual add (outF == resid allowed)
            const int win = gr / 196, tk = gr - win * 196;
            const int img = win / 25, wrem = win - img * 25, wy = wrem / 5, wx = wrem - wy * 5;
            const int ty = tk / WINS, tx = tk - ty * WINS;
            const int y = wy * WINS + ty, x = wx * WINS + tx;
            if (y < 64 && x < 64) {
              const size_t o = (size_t)((img << 12) + (y << 6) + x) * DIMC + gc;
              outF[o] = resid[o] + v;
            }
          } else {
            outB[(size_t)gr * N + gc] = f2bf(v);
          }
        }
      }
    }
  }
}

// ---------------- fused windowed attention, MFMA flash-style ----------------
// block = (win, head); qkvR layout: per (win,head): [Q(196x64) | K(196x64) | V(196x64)]
__global__ __launch_bounds__(256, 2)
void attn_k(const u16* __restrict__ qkvR, const float* __restrict__ relh,
            const float* __restrict__ relw, u16* __restrict__ out) {
  const int blk = (int)blockIdx.x;
  const int win = blk / HEADS, h = blk - win * HEADS;
  const int t = (int)threadIdx.x, w = t >> 6, lane = t & 63;
  const int li = lane & 15, g = lane >> 4;

  __shared__ u16 Kt[64 * 64];     // j x d, swizzled (8-elem blocks XOR row&7)
  __shared__ u16 Vt[64 * 64];     // d x j (transposed), swizzled
  __shared__ u16 Pb[4 * 64 * 64]; // per-wave P tiles; first 8KB aliases rel buf in phase A
  __shared__ u16 dhw[196 * 32];   // [i][0..13]=dh, [i][16..29]=dw (bf16)

  const u16* Qb = qkvR + (size_t)(win * HEADS + h) * 3 * NTOK * 64;
  const u16* Kb = Qb + NTOK * 64;
  const u16* Vb = Kb + NTOK * 64;

  // ---- Q fragments (A-operand: lane holds Q[row=li][k=g*8+e], rows clamped) ----
  v8bf qf[4][2];
#pragma unroll
  for (int mf = 0; mf < 4; ++mf) {
    int i = 64 * w + mf * 16 + li; if (i > 195) i = 195;
#pragma unroll
    for (int ks = 0; ks < 2; ++ks)
      qf[mf][ks] = *(const v8bf*)(Qb + (size_t)i * 64 + ks * 32 + g * 8);
  }

  // ---- phase A: rel tables via MFMA ----
  u16* relb = Pb; // [2][32 rows][64 cols], swizzled like Kt
  for (int idx = t; idx < 2 * 32 * 64; idx += 256) {
    const int which = idx >> 11, rem = idx & 2047, r = rem >> 6, c = rem & 63;
    const float v = (r < 27) ? (which ? relw[r * 64 + c] : relh[r * 64 + c]) : 0.f;
    relb[which * 2048 + r * 64 + (((c >> 3) ^ (r & 7)) * 8) + (c & 7)] = f2bf(v);
  }
  __syncthreads();
  {
    f32x4 dacc[4][2], eacc[4][2];
    const f32x4 vz = {0.f, 0.f, 0.f, 0.f};
#pragma unroll
    for (int mf = 0; mf < 4; ++mf)
#pragma unroll
      for (int nf = 0; nf < 2; ++nf) { dacc[mf][nf] = vz; eacc[mf][nf] = vz; }
#pragma unroll
    for (int ks = 0; ks < 2; ++ks)
#pragma unroll
      for (int nf = 0; nf < 2; ++nf) {
        const int row = nf * 16 + li;
        const int off = row * 64 + (((ks * 4 + g) ^ (li & 7)) * 8);
        v8bf bh = *(const v8bf*)&relb[off];
        v8bf bw = *(const v8bf*)&relb[2048 + off];
#pragma unroll
        for (int mf = 0; mf < 4; ++mf) {
          dacc[mf][nf] = __builtin_amdgcn_mfma_f32_16x16x32_bf16(qf[mf][ks], bh, dacc[mf][nf], 0, 0, 0);
          eacc[mf][nf] = __builtin_amdgcn_mfma_f32_16x16x32_bf16(qf[mf][ks], bw, eacc[mf][nf], 0, 0, 0);
        }
      }
    // scatter D,E -> dhw (bijective per row)
#pragma unroll
    for (int mf = 0; mf < 4; ++mf)
#pragma unroll
      for (int nf = 0; nf < 2; ++nf)
#pragma unroll
        for (int r = 0; r < 4; ++r) {
          const int i = 64 * w + mf * 16 + 4 * g + r;
          if (i < 196) {
            const int c = nf * 16 + li;
            const int ih = (i * 2341) >> 15, iw = i - ih * 14;
            const int jh = ih + 13 - c;
            if ((unsigned)jh < 14u) dhw[i * 32 + jh] = f2bf(dacc[mf][nf][r]);
            const int jw = iw + 13 - c;
            if ((unsigned)jw < 14u) dhw[i * 32 + 16 + jw] = f2bf(eacc[mf][nf][r]);
          }
        }
  }
  __syncthreads();

  // ---- phase B: flash over j-tiles ----
  f32x4 oacc[4][4];
  const f32x4 vz = {0.f, 0.f, 0.f, 0.f};
#pragma unroll
  for (int a = 0; a < 4; ++a)
#pragma unroll
    for (int b = 0; b < 4; ++b) oacc[a][b] = vz;
  float mrun[16], lrun[16];
#pragma unroll
  for (int a = 0; a < 16; ++a) { mrun[a] = -1e30f; lrun[a] = 0.f; }

  u16* Pw = Pb + w * 4096; // own P tile [64 i][64 j] swizzled

  for (int jt = 0; jt < 4; ++jt) {
    const int j0 = jt * 64;
    const int njf = (jt < 3) ? 4 : 2;   // valid 16-col j-fragments this tile
    const int nks = (jt < 3) ? 2 : 1;   // PV k-steps this tile

    // stage K tile (global_load_lds, linear dest + inverse-swizzled source)
#pragma unroll
    for (int is = 0; is < 2; ++is) {
      const int rbase = 16 * w + is * 8;
      const int row = rbase + (lane >> 3);
      int jg = j0 + row; if (jg > 195) jg = 195;
      const int cbs = (lane & 7) ^ (row & 7);
      cp16(Kb + (size_t)jg * 64 + cbs * 8, &Kt[rbase * 64]);
    }
    // stage V transposed (reg-stage): wave w covers d-slab [16w,16w+16), all 64 j
    {
      const int jl = t & 63;
      int jg = j0 + jl; if (jg > 195) jg = 195;
      const int d0 = (t >> 6) * 16;
      const u16* vp = Vb + (size_t)jg * 64 + d0;
      v8u v0 = *(const v8u*)vp, v1 = *(const v8u*)(vp + 8);
#pragma unroll
      for (int e = 0; e < 8; ++e) {
        const int da = d0 + e, db = d0 + 8 + e;
        Vt[da * 64 + (((jl >> 3) ^ (da & 7)) * 8) + (jl & 7)] = v0[e];
        Vt[db * 64 + (((jl >> 3) ^ (db & 7)) * 8) + (jl & 7)] = v1[e];
      }
    }
    __syncthreads();

    // QK^T
    f32x4 sacc[4][4];
#pragma unroll
    for (int a = 0; a < 4; ++a)
#pragma unroll
      for (int b = 0; b < 4; ++b) sacc[a][b] = vz;
#pragma unroll
    for (int ks = 0; ks < 2; ++ks)
#pragma unroll
      for (int jf = 0; jf < 4; ++jf) if (jf < njf) {
        const int row = jf * 16 + li;
        v8bf kb = *(const v8bf*)&Kt[row * 64 + (((ks * 4 + g) ^ (li & 7)) * 8)];
#pragma unroll
        for (int mf = 0; mf < 4; ++mf)
          sacc[mf][jf] = __builtin_amdgcn_mfma_f32_16x16x32_bf16(qf[mf][ks], kb, sacc[mf][jf], 0, 0, 0);
      }

    // bias + mask
#pragma unroll
    for (int jf = 0; jf < 4; ++jf) if (jf < njf) {
      const int j = j0 + jf * 16 + li;
      const bool jok = j < 196;
      const int jh = (j * 2341) >> 15;
      const int jw = j - jh * 14;
#pragma unroll
      for (int mf = 0; mf < 4; ++mf)
#pragma unroll
        for (int r = 0; r < 4; ++r) {
          const int i = 64 * w + mf * 16 + 4 * g + r;
          float v;
          if (jok && i < 196)
            v = sacc[mf][jf][r] * 0.125f + bf2f(dhw[i * 32 + jh]) + bf2f(dhw[i * 32 + 16 + jw]);
          else v = -1e30f;
          sacc[mf][jf][r] = v;
        }
    }

    // online softmax update + write P
#pragma unroll
    for (int mf = 0; mf < 4; ++mf)
#pragma unroll
      for (int r = 0; r < 4; ++r) {
        float tmx = -1e30f;
#pragma unroll
        for (int jf = 0; jf < 4; ++jf) if (jf < njf) tmx = fmaxf(tmx, sacc[mf][jf][r]);
#pragma unroll
        for (int o = 1; o < 16; o <<= 1) tmx = fmaxf(tmx, __shfl_xor(tmx, o, 16));
        const int idx = mf * 4 + r;
        const float mnew = fmaxf(mrun[idx], tmx);
        const float sf = __expf(mrun[idx] - mnew);
        mrun[idx] = mnew;
        float ls = 0.f;
#pragma unroll
        for (int jf = 0; jf < 4; ++jf) if (jf < njf) {
          const float p = __expf(sacc[mf][jf][r] - mnew);
          sacc[mf][jf][r] = p;
          ls += p;
        }
#pragma unroll
        for (int o = 1; o < 16; o <<= 1) ls += __shfl_xor(ls, o, 16);
        lrun[idx] = lrun[idx] * sf + ls;
#pragma unroll
        for (int nf = 0; nf < 4; ++nf) oacc[mf][nf][r] *= sf;
      }
#pragma unroll
    for (int jf = 0; jf < 4; ++jf) if (jf < njf) {
      const int j = jf * 16 + li;
#pragma unroll
      for (int mf = 0; mf < 4; ++mf)
#pragma unroll
        for (int r = 0; r < 4; ++r) {
          const int il = mf * 16 + 4 * g + r;
          Pw[il * 64 + (((j >> 3) ^ (il & 7)) * 8) + (j & 7)] = f2bf(sacc[mf][jf][r]);
        }
    }
    __syncthreads();   // P visible + Vt ready for all

    // PV: O += P(64i x 64j) * V(64j x 64d)
#pragma unroll
    for (int ks = 0; ks < 2; ++ks) if (ks < nks) {
      v8bf pa[4];
#pragma unroll
      for (int mf = 0; mf < 4; ++mf) {
        const int row = mf * 16 + li;
        pa[mf] = *(const v8bf*)&Pw[row * 64 + (((ks * 4 + g) ^ (li & 7)) * 8)];
      }
#pragma unroll
      for (int nf = 0; nf < 4; ++nf) {
        const int row = nf * 16 + li;
        v8bf vb = *(const v8bf*)&Vt[row * 64 + (((ks * 4 + g) ^ (li & 7)) * 8)];
#pragma unroll
        for (int mf = 0; mf < 4; ++mf)
          oacc[mf][nf] = __builtin_amdgcn_mfma_f32_16x16x32_bf16(pa[mf], vb, oacc[mf][nf], 0, 0, 0);
      }
    }
    __syncthreads();   // before next tile's staging overwrites Kt/Vt
  }

  // ---- epilogue: transpose through own Pw tile, then 16B vector stores ----
  float rinv[16];
#pragma unroll
  for (int a = 0; a < 16; ++a) rinv[a] = 1.0f / lrun[a];
#pragma unroll
  for (int mf = 0; mf < 4; ++mf)
#pragma unroll
    for (int nf = 0; nf < 4; ++nf)
#pragma unroll
      for (int r = 0; r < 4; ++r) {
        const int il = mf * 16 + 4 * g + r;
        const int d = nf * 16 + li;
        Pw[il * 64 + (((d >> 3) ^ (il & 7)) * 8) + (d & 7)] = f2bf(oacc[mf][nf][r] * rinv[mf * 4 + r]);
      }
  __syncthreads();
#pragma unroll
  for (int pass = 0; pass < 8; ++pass) {
    const int row = pass * 8 + (lane >> 3);
    const int i = 64 * w + row;
    const int seg = lane & 7;
    if (i < 196) {
      const int c16 = seg ^ (row & 7);
      v8u val = *(const v8u*)&Pw[row * 64 + c16 * 8];
      *(v8u*)(out + (size_t)(win * NTOK + i) * DIMC + h * 64 + seg * 8) = val;
    }
  }
}

extern "C" void kernel_launch(void* const* d_in, const int* in_sizes, int n_in,
                              void* d_out, int out_size, void* d_ws, size_t ws_size,
                              hipStream_t stream) {
  (void)in_sizes; (void)n_in; (void)out_size; (void)ws_size;
  const float* x0     = (const float*)d_in[0];
  const float* an1_w  = (const float*)d_in[1];
  const float* an1_b  = (const float*)d_in[2];
  const float* ad1_W  = (const float*)d_in[3];
  const float* ad1_b  = (const float*)d_in[4];
  const float* ac1_W  = (const float*)d_in[5];
  const float* ac1_b  = (const float*)d_in[6];
  const float* au1_W  = (const float*)d_in[7];
  const float* au1_b  = (const float*)d_in[8];
  const float* an2_w  = (const float*)d_in[9];
  const float* an2_b  = (const float*)d_in[10];
  const float* ad2_W  = (const float*)d_in[11];
  const float* ad2_b  = (const float*)d_in[12];
  const float* ac2_W  = (const float*)d_in[13];
  const float* ac2_b  = (const float*)d_in[14];
  const float* au2_W  = (const float*)d_in[15];
  const float* au2_b  = (const float*)d_in[16];
  const float* n1_w   = (const float*)d_in[17];
  const float* n1_b   = (const float*)d_in[18];
  const float* qkv_W  = (const float*)d_in[19];
  const float* qkv_b  = (const float*)d_in[20];
  const float* facu_W = (const float*)d_in[21];
  const float* facv_W = (const float*)d_in[22];
  const float* qfac_W = (const float*)d_in[23];
  const float* vfac_W = (const float*)d_in[24];
  const float* rel_h  = (const float*)d_in[25];
  const float* rel_w  = (const float*)d_in[26];
  const float* proj_W = (const float*)d_in[27];
  const float* proj_b = (const float*)d_in[28];
  const float* n2_w   = (const float*)d_in[29];
  const float* n2_b   = (const float*)d_in[30];
  const float* mlp_W1 = (const float*)d_in[31];
  const float* mlp_b1 = (const float*)d_in[32];
  const float* mlp_W2 = (const float*)d_in[33];
  const float* mlp_b2 = (const float*)d_in[34];

  char* ws = (char*)d_ws;
  size_t off = 0;
  auto alloc = [&](size_t bytes) -> void* {
    void* p = (void*)(ws + off);
    off += (bytes + 255) & ~(size_t)255;
    return p;
  };
  u16*  bufA  = (u16*)alloc((size_t)MS * 3072 * 2);      // qkvR bf16 / mlp hidden bf16
  u16*  bufB  = (u16*)alloc((size_t)MWP * DIMC * 2);     // LN/window tokens + attn out, bf16
  float* bufX = (float*)alloc((size_t)MS * DIMC * 4);    // residual stream f32
  u16*  bufD  = (u16*)alloc((size_t)MS * ACCH * 2);      // adapter down out
  u16*  bufE  = (u16*)alloc((size_t)MS * ACCH * 2);      // adapter conv+gelu out
  u16*  Wcomb = (u16*)alloc((size_t)2304 * 768 * 2);
  u16*  Wproj = (u16*)alloc((size_t)768 * 768 * 2);
  u16*  Wm1   = (u16*)alloc((size_t)3072 * 768 * 2);
  u16*  Wm2   = (u16*)alloc((size_t)768 * 3072 * 2);
  u16*  Wad1  = (u16*)alloc((size_t)256 * 768 * 2);
  u16*  Wau1  = (u16*)alloc((size_t)768 * 192 * 2);
  u16*  Wcv1  = (u16*)alloc((size_t)256 * 5184 * 2);
  u16*  Wad2  = (u16*)alloc((size_t)256 * 768 * 2);
  u16*  Wau2  = (u16*)alloc((size_t)768 * 192 * 2);
  u16*  Wcv2  = (u16*)alloc((size_t)256 * 5184 * 2);
  float* Uq   = (float*)alloc(768 * 32 * 4);
  float* Uv   = (float*)alloc(768 * 32 * 4);
  u16*  zrow  = (u16*)alloc(256);

  // ---- weight prep (every launch; deterministic) ----
  k_zero16<<<1, 256, 0, stream>>>(zrow, 128);
  k_compute_U<<<192, 256, 0, stream>>>(facu_W, qfac_W, vfac_W, Uq, Uv);
  k_build_wcomb<<<(2304 * 768 + 255) / 256, 256, 0, stream>>>(qkv_W, Uq, Uv, facv_W, Wcomb);
  k_cast_pad<<<(768 * 768 + 255) / 256, 256, 0, stream>>>(proj_W, Wproj, 768, 768, 768);
  k_cast_pad<<<(3072 * 768 + 255) / 256, 256, 0, stream>>>(mlp_W1, Wm1, 3072, 768, 3072);
  k_cast_pad<<<(768 * 3072 + 255) / 256, 256, 0, stream>>>(mlp_W2, Wm2, 768, 3072, 768);
  k_cast_pad<<<(256 * 768 + 255) / 256, 256, 0, stream>>>(ad1_W, Wad1, 192, 768, 256);
  k_cast_pad<<<(768 * 192 + 255) / 256, 256, 0, stream>>>(au1_W, Wau1, 768, 192, 768);
  k_cast_pad<<<(256 * 768 + 255) / 256, 256, 0, stream>>>(ad2_W, Wad2, 192, 768, 256);
  k_cast_pad<<<(768 * 192 + 255) / 256, 256, 0, stream>>>(au2_W, Wau2, 768, 192, 768);
  k_conv_repack<<<(256 * 5184 + 255) / 256, 256, 0, stream>>>(ac1_W, Wcv1);
  k_conv_repack<<<(256 * 5184 + 255) / 256, 256, 0, stream>>>(ac2_W, Wcv2);

  // ---- adapter 1: x1 = x0 + up(gelu(conv(down(LN(x0))))) ----
  ln_k<false><<<MS, 256, 0, stream>>>(x0, an1_w, an1_b, bufB);
  gemm_bt<1, false><<<dim3(2, 160), 256, 0, stream>>>(bufB, Wad1, ad1_b, nullptr, nullptr, bufD, MS, 192, 768, nullptr);
  gemm_bt<2, true><<<dim3(2, 160), 256, 0, stream>>>(bufD, Wcv1, ac1_b, nullptr, nullptr, bufE, MS, 192, 5184, zrow);
  gemm_bt<3, false><<<dim3(6, 160), 256, 0, stream>>>(bufE, Wau1, au1_b, x0, bufX, nullptr, MS, 768, 192, nullptr);

  // ---- windowed attention ----
  ln_k<true><<<MWP, 256, 0, stream>>>(bufX, n1_w, n1_b, bufB);
  gemm_bt<4, false><<<dim3(18, 192), 256, 0, stream>>>(bufB, Wcomb, qkv_b, nullptr, nullptr, bufA, MW, 2304, 768, nullptr);
  attn_k<<<125 * HEADS, 256, 0, stream>>>(bufA, rel_h, rel_w, bufB);
  gemm_bt<5, false><<<dim3(6, 192), 256, 0, stream>>>(bufB, Wproj, proj_b, bufX, bufX, nullptr, MW, 768, 768, nullptr);

  // ---- adapter 2 ----
  ln_k<false><<<MS, 256, 0, stream>>>(bufX, an2_w, an2_b, bufB);
  gemm_bt<1, false><<<dim3(2, 160), 256, 0, stream>>>(bufB, Wad2, ad2_b, nullptr, nullptr, bufD, MS, 192, 768, nullptr);
  gemm_bt<2, true><<<dim3(2, 160), 256, 0, stream>>>(bufD, Wcv2, ac2_b, nullptr, nullptr, bufE, MS, 192, 5184, zrow);
  gemm_bt<3, false><<<dim3(6, 160), 256, 0, stream>>>(bufE, Wau2, au2_b, bufX, bufX, nullptr, MS, 768, 192, nullptr);

  // ---- MLP ----
  ln_k<false><<<MS, 256, 0, stream>>>(bufX, n2_w, n2_b, bufB);
  gemm_bt<2, false><<<dim3(24, 160), 256, 0, stream>>>(bufB, Wm1, mlp_b1, nullptr, nullptr, bufA, MS, 3072, 768, nullptr);
  gemm_bt<3, false><<<dim3(6, 160), 256, 0, stream>>>(bufA, Wm2, mlp_b2, bufX, (float*)d_out, nullptr, MS, 768, 3072, nullptr);
}

// Round 4
// 1427.328 us; speedup vs baseline: 1.1743x; 1.1743x over previous
//
#include <hip/hip_runtime.h>

typedef unsigned short u16;
typedef __bf16 v8bf __attribute__((ext_vector_type(8)));
typedef unsigned short v8u __attribute__((ext_vector_type(8)));
typedef float f32x4 __attribute__((ext_vector_type(4)));

static constexpr int DIMC = 768;
static constexpr int HEADS = 12;
static constexpr int WINS  = 14;
static constexpr int ACCH  = 192;   // adapter channels
static constexpr int NTOK  = 196;   // 14*14
static constexpr int MW    = 24500; // 125 windows * 196 tokens
static constexpr int MWP   = 24576; // padded to tile multiple
static constexpr int MS    = 20480; // 5*64*64 spatial tokens

__device__ __forceinline__ float bf2f(u16 u) {
  union { unsigned int i; float f; } x; x.i = ((unsigned int)u) << 16; return x.f;
}
__device__ __forceinline__ u16 f2bf(float f) {
  union { float f; unsigned int i; } x; x.f = f;
  unsigned int r = x.i + 0x7fffu + ((x.i >> 16) & 1u);
  return (u16)(r >> 16);
}
__device__ __forceinline__ float gelu_f(float x) {
  return 0.5f * x * (1.0f + erff(x * 0.70710678118654752440f));
}
// async global->LDS, 16B per lane. LDS dest is wave-uniform base + lane*16.
__device__ __forceinline__ void cp16(const u16* g, u16* l) {
  __builtin_amdgcn_global_load_lds(
      (const __attribute__((address_space(1))) unsigned int*)(const void*)g,
      (__attribute__((address_space(3))) unsigned int*)(void*)l, 16, 0, 0);
}

// ---------------- weight prep ----------------
__global__ void k_zero16(u16* p, int n) {
  int i = blockIdx.x * 256 + threadIdx.x;
  if (i < n) p[i] = 0;
}
// U[k][b] = sum_a facu_W[a][k] * fac_W[b][a]   (fac = qfac or vfac)
__global__ void k_compute_U(const float* __restrict__ facu, const float* __restrict__ qfac,
                            const float* __restrict__ vfac, float* __restrict__ Uq,
                            float* __restrict__ Uv) {
  int idx = blockIdx.x * 256 + threadIdx.x;
  if (idx >= 2 * 768 * 32) return;
  const int which = idx / (768 * 32);
  const int rem = idx - which * 768 * 32;
  const int k = rem >> 5, b = rem & 31;
  const float* fac = which ? vfac : qfac;
  float s = 0.f;
  for (int a = 0; a < 32; ++a) s += facu[a * 768 + k] * fac[b * 32 + a];
  (which ? Uv : Uq)[rem] = s;
}
// Wc[n][k] = qkv_W[n][k] (+ sum_b U{q,v}[k][b]*facv_W[n'][b] for q/v blocks), cast bf16
__global__ void k_build_wcomb(const float* __restrict__ qkvW, const float* __restrict__ Uq,
                              const float* __restrict__ Uv, const float* __restrict__ facv,
                              u16* __restrict__ Wc) {
  int idx = blockIdx.x * 256 + threadIdx.x;
  if (idx >= 2304 * 768) return;
  const int n = idx / 768, k = idx - n * 768;
  float v = qkvW[idx];
  if (n < 768) {
    float s = 0.f;
    for (int b = 0; b < 32; ++b) s += Uq[k * 32 + b] * facv[n * 32 + b];
    v += s;
  } else if (n >= 1536) {
    const int nn = n - 1536;
    float s = 0.f;
    for (int b = 0; b < 32; ++b) s += Uv[k * 32 + b] * facv[nn * 32 + b];
    v += s;
  }
  Wc[idx] = f2bf(v);
}
__global__ void k_cast_pad(const float* __restrict__ src, u16* __restrict__ dst,
                           int rows, int cols, int rowsPad) {
  int idx = blockIdx.x * 256 + threadIdx.x;
  if (idx >= rowsPad * cols) return;
  const int r = idx / cols;
  dst[idx] = (r < rows) ? f2bf(src[idx]) : (u16)0;
}
// ac_W [192][192][3][3][3] -> Wconv [256 pad][27*192] with k = tap*192+ci
__global__ void k_conv_repack(const float* __restrict__ src, u16* __restrict__ dst) {
  int idx = blockIdx.x * 256 + threadIdx.x;
  if (idx >= 256 * 5184) return;
  const int co = idx / 5184;
  const int rem = idx - co * 5184;
  const int tap = rem / 192, ci = rem - tap * 192;
  dst[idx] = (co < 192) ? f2bf(src[co * 5184 + ci * 27 + tap]) : (u16)0;
}

// ---------------- LayerNorm (optionally fused window-partition) ----------------
template<bool WINDOWED>
__global__ __launch_bounds__(256)
void ln_k(const float* __restrict__ X, const float* __restrict__ w,
          const float* __restrict__ b, u16* __restrict__ out) {
  const int r = (int)blockIdx.x;
  const int t = (int)threadIdx.x;
  int src = r;
  bool zero = false;
  if (WINDOWED) {
    if (r >= MW) zero = true;
    else {
      const int win = r / NTOK, tk = r - win * NTOK;
      const int img = win / 25, wrem = win - img * 25, wy = wrem / 5, wx = wrem - wy * 5;
      const int ty = tk / WINS, tx = tk - ty * WINS;
      const int y = wy * WINS + ty, x = wx * WINS + tx;
      if (y >= 64 || x >= 64) zero = true;
      else src = (img << 12) + (y << 6) + x;
    }
  }
  u16* orow = out + (size_t)r * DIMC;
  if (zero) {
    for (int c = t; c < DIMC; c += 256) orow[c] = 0;
    return;
  }
  const float* xr = X + (size_t)src * DIMC;
  const float v0 = xr[t], v1 = xr[t + 256], v2 = xr[t + 512];
  float s = v0 + v1 + v2, ss = v0 * v0 + v1 * v1 + v2 * v2;
#pragma unroll
  for (int o = 32; o > 0; o >>= 1) { s += __shfl_xor(s, o, 64); ss += __shfl_xor(ss, o, 64); }
  __shared__ float red[8];
  const int wave = t >> 6, lane = t & 63;
  if (lane == 0) { red[wave] = s; red[4 + wave] = ss; }
  __syncthreads();
  s = red[0] + red[1] + red[2] + red[3];
  ss = red[4] + red[5] + red[6] + red[7];
  const float mean = s * (1.0f / 768.0f);
  const float var = ss * (1.0f / 768.0f) - mean * mean;
  const float rstd = rsqrtf(var + 1e-5f);
  orow[t]       = f2bf((v0 - mean) * rstd * w[t]       + b[t]);
  orow[t + 256] = f2bf((v1 - mean) * rstd * w[t + 256] + b[t + 256]);
  orow[t + 512] = f2bf((v2 - mean) * rstd * w[t + 512] + b[t + 512]);
}

// ---------------- GEMM: C[M,N] = A[M,K] @ B[N,K]^T (+bias, epilogues) ----------------
// EPI: 0 = f32 out (bias); 1 = bf16 out (bias); 2 = bf16 out (bias+GELU);
//      3 = f32 out (bias+residual); 4 = bf16 qkv-scatter per (win,head);
//      5 = f32 window-unpartition + in-place residual add
// CONV: A rows gathered as 3x3x3 SAME conv over [5][64][64][192]; K = tap*192+ci
template<int EPI, bool CONV>
__global__ __launch_bounds__(256)
void gemm_bt(const u16* __restrict__ A, const u16* __restrict__ B,
             const float* __restrict__ bias, const float* __restrict__ resid,
             float* __restrict__ outF, u16* __restrict__ outB,
             int M, int N, int K, const u16* __restrict__ zrow) {
  __shared__ u16 At[128 * 64];
  __shared__ u16 Bt[128 * 64];
  const int bm = (int)blockIdx.y, bn = (int)blockIdx.x;
  const int t = (int)threadIdx.x;
  const int wave = t >> 6, lane = t & 63;
  const int wm = wave >> 1, wn = wave & 1;
  const int lrow = lane >> 3;                // 0..7 (row within 8-row group)
  const int c16s = (lane & 7) ^ lrow;        // pre-swizzled source col16
  const int li = lane & 15, lq = lane >> 4;

  f32x4 acc[4][4];
  const f32x4 vzero = {0.f, 0.f, 0.f, 0.f};
#pragma unroll
  for (int a = 0; a < 4; ++a)
#pragma unroll
    for (int b = 0; b < 4; ++b) acc[a][b] = vzero;

  const int nk = K >> 6;
  for (int kt = 0; kt < nk; ++kt) {
    int cD = 0, cY = 0, cX = 0, cblk = 0;
    if (CONV) {
      const int tap = kt / 3;
      cblk = (kt - tap * 3) << 6;
      const int kd = tap / 9, r9 = tap - kd * 9, ky = r9 / 3;
      cD = kd - 1; cY = ky - 1; cX = (r9 - ky * 3) - 1;
    }
#pragma unroll
    for (int i = 0; i < 4; ++i) {           // stage A: 128x64 bf16
      const int r0 = i * 32 + wave * 8;
      const int grow = bm * 128 + r0 + lrow;
      const u16* src;
      if (CONV) {
        const int d = (grow >> 12) + cD, y = ((grow >> 6) & 63) + cY, x = (grow & 63) + cX;
        if ((unsigned)d < 5u && (unsigned)y < 64u && (unsigned)x < 64u)
          src = A + (size_t)((d << 12) + (y << 6) + x) * ACCH + cblk + c16s * 8;
        else
          src = zrow + c16s * 8;
      } else {
        src = A + (size_t)grow * K + (kt << 6) + c16s * 8;
      }
      cp16(src, &At[r0 * 64]);
    }
#pragma unroll
    for (int i = 0; i < 4; ++i) {           // stage B: 128x64 bf16
      const int r0 = i * 32 + wave * 8;
      const int grow = bn * 128 + r0 + lrow;
      cp16(B + (size_t)grow * K + (kt << 6) + c16s * 8, &Bt[r0 * 64]);
    }
    __syncthreads();                         // drains vmcnt for global_load_lds
#pragma unroll
    for (int kk = 0; kk < 2; ++kk) {
      v8bf af[4], bg[4];
#pragma unroll
      for (int mf = 0; mf < 4; ++mf) {
        const int row = wm * 64 + mf * 16 + li;
        const int c16 = (kk * 4 + lq) ^ (li & 7);
        af[mf] = *(const v8bf*)&At[row * 64 + c16 * 8];
      }
#pragma unroll
      for (int nf = 0; nf < 4; ++nf) {
        const int row = wn * 64 + nf * 16 + li;
        const int c16 = (kk * 4 + lq) ^ (li & 7);
        bg[nf] = *(const v8bf*)&Bt[row * 64 + c16 * 8];
      }
#pragma unroll
      for (int mf = 0; mf < 4; ++mf)
#pragma unroll
        for (int nf = 0; nf < 4; ++nf)
          acc[mf][nf] = __builtin_amdgcn_mfma_f32_16x16x32_bf16(af[mf], bg[nf], acc[mf][nf], 0, 0, 0);
    }
    __syncthreads();
  }

#pragma unroll
  for (int mf = 0; mf < 4; ++mf) {
#pragma unroll
    for (int nf = 0; nf < 4; ++nf) {
      const int gc = bn * 128 + wn * 64 + nf * 16 + li;
#pragma unroll
      for (int r = 0; r < 4; ++r) {
        const int gr = bm * 128 + wm * 64 + mf * 16 + lq * 4 + r;
        if (gr < M && gc < N) {
          float v = acc[mf][nf][r] + bias[gc];
          if (EPI == 2) v = gelu_f(v);
          if (EPI == 3) v += resid[(size_t)gr * N + gc];
          if (EPI == 0 || EPI == 3) {
            outF[(size_t)gr * N + gc] = v;
          } else if (EPI == 4) {
            // scatter qkv into per-(win,head) contiguous [Q|K|V][196][64]
            const int sec = gc / 768;
            const int hm = gc - sec * 768;
            const int hd = hm >> 6, dd = hm & 63;
            const int win = gr / 196, tk = gr - win * 196;
            outB[(size_t)(((win * HEADS + hd) * 3 + sec) * NTOK + tk) * 64 + dd] = f2bf(v);
          } else if (EPI == 5) {
            // window-unpartition + in-place residual add (outF == resid allowed)
            const int win = gr / 196, tk = gr - win * 196;
            const int img = win / 25, wrem = win - img * 25, wy = wrem / 5, wx = wrem - wy * 5;
            const int ty = tk / WINS, tx = tk - ty * WINS;
            const int y = wy * WINS + ty, x = wx * WINS + tx;
            if (y < 64 && x < 64) {
              const size_t o = (size_t)((img << 12) + (y << 6) + x) * DIMC + gc;
              outF[o] = resid[o] + v;
            }
          } else {
            outB[(size_t)gr * N + gc] = f2bf(v);
          }
        }
      }
    }
  }
}

// ---------------- fused windowed attention, MFMA flash-style, spill-free ----------------
// block = (win, head); qkvR layout per (win,head): [Q(196x64) | K(196x64) | V(196x64)]
// Register budget: acc = oacc(64)+sacc(64) AGPR; arch ~90 (Q lives in LDS, P chunked 64x32).
__global__ __launch_bounds__(256)
void attn_k(const u16* __restrict__ qkvR, const float* __restrict__ relh,
            const float* __restrict__ relw, u16* __restrict__ out) {
  const int blk = (int)blockIdx.x;
  const int win = blk / HEADS, h = blk - win * HEADS;
  const int t = (int)threadIdx.x, w = t >> 6, lane = t & 63;
  const int li = lane & 15, g = lane >> 4;

  __shared__ u16 Qs[256 * 64];    // 32 KB, swizzled rows (clamped stage of 196 rows)
  __shared__ u16 Kt[64 * 64];     // 8 KB [j][d], swizzled (cp16 linear dest)
  __shared__ u16 Vt[64 * 64];     // 8 KB [d][j], seg-XOR swizzled
  __shared__ u16 Pb[4 * 64 * 32]; // 16 KB per-wave P/O chunks; aliases rel buf in phase A
  __shared__ u16 dhw[196 * 32];   // [i][0..13]=dh, [i][16..29]=dw (bf16)

  const u16* Qb = qkvR + (size_t)(win * HEADS + h) * 3 * NTOK * 64;
  const u16* Kb = Qb + NTOK * 64;
  const u16* Vb = Kb + NTOK * 64;

  // ---- stage Q: 256 rows (sources clamped to row 195), linear dest + pre-swizzled src ----
#pragma unroll
  for (int s = 0; s < 8; ++s) {
    const int rbase = s * 32 + w * 8;
    const int row = rbase + (lane >> 3);
    const int src = row < NTOK ? row : NTOK - 1;
    const int cbs = (lane & 7) ^ (row & 7);
    cp16(Qb + (size_t)src * 64 + cbs * 8, &Qs[rbase * 64]);
  }
  // ---- stage rel tables into Pb (phase-A alias) ----
  u16* relb = Pb; // [2][32 rows][64 cols], swizzled like Kt
  for (int idx = t; idx < 2 * 32 * 64; idx += 256) {
    const int which = idx >> 11, rem = idx & 2047, r = rem >> 6, c = rem & 63;
    const float v = (r < 27) ? (which ? relw[r * 64 + c] : relh[r * 64 + c]) : 0.f;
    relb[which * 2048 + r * 64 + (((c >> 3) ^ (r & 7)) * 8) + (c & 7)] = f2bf(v);
  }
  __syncthreads();

  // ---- phase A: rel-pos tables via MFMA (Q from LDS) ----
  {
    f32x4 dacc[4][2], eacc[4][2];
    const f32x4 vz = {0.f, 0.f, 0.f, 0.f};
#pragma unroll
    for (int mf = 0; mf < 4; ++mf)
#pragma unroll
      for (int nf = 0; nf < 2; ++nf) { dacc[mf][nf] = vz; eacc[mf][nf] = vz; }
#pragma unroll
    for (int ks = 0; ks < 2; ++ks) {
      v8bf qk[4];
#pragma unroll
      for (int mf = 0; mf < 4; ++mf) {
        const int row = 64 * w + mf * 16 + li;
        qk[mf] = *(const v8bf*)&Qs[row * 64 + (((ks * 4 + g) ^ (li & 7)) * 8)];
      }
#pragma unroll
      for (int nf = 0; nf < 2; ++nf) {
        const int row = nf * 16 + li;
        const int off = row * 64 + (((ks * 4 + g) ^ (li & 7)) * 8);
        v8bf bh = *(const v8bf*)&relb[off];
        v8bf bw = *(const v8bf*)&relb[2048 + off];
#pragma unroll
        for (int mf = 0; mf < 4; ++mf) {
          dacc[mf][nf] = __builtin_amdgcn_mfma_f32_16x16x32_bf16(qk[mf], bh, dacc[mf][nf], 0, 0, 0);
          eacc[mf][nf] = __builtin_amdgcn_mfma_f32_16x16x32_bf16(qk[mf], bw, eacc[mf][nf], 0, 0, 0);
        }
      }
    }
    // scatter D,E -> dhw (bijective per row)
#pragma unroll
    for (int mf = 0; mf < 4; ++mf)
#pragma unroll
      for (int nf = 0; nf < 2; ++nf)
#pragma unroll
        for (int r = 0; r < 4; ++r) {
          const int i = 64 * w + mf * 16 + 4 * g + r;
          if (i < 196) {
            const int c = nf * 16 + li;
            const int ih = (i * 2341) >> 15, iw = i - ih * 14;
            const int jh = ih + 13 - c;
            if ((unsigned)jh < 14u) dhw[i * 32 + jh] = f2bf(dacc[mf][nf][r]);
            const int jw = iw + 13 - c;
            if ((unsigned)jw < 14u) dhw[i * 32 + 16 + jw] = f2bf(eacc[mf][nf][r]);
          }
        }
  }
  __syncthreads();   // phase-A reads of relb done; Pb free for P chunks

  // ---- phase B: flash over 4 j-tiles of 64 ----
  f32x4 oacc[4][4];
  const f32x4 vz = {0.f, 0.f, 0.f, 0.f};
#pragma unroll
  for (int a = 0; a < 4; ++a)
#pragma unroll
    for (int b = 0; b < 4; ++b) oacc[a][b] = vz;
  float mrun[16], lrun[16];
#pragma unroll
  for (int a = 0; a < 16; ++a) { mrun[a] = -1e30f; lrun[a] = 0.f; }

  u16* Pw = Pb + w * 2048; // own chunk [64 i][32 j]

  for (int jt = 0; jt < 4; ++jt) {
    const int j0 = jt * 64;
    const int njf = (jt < 3) ? 4 : 1;    // valid 16-col j-fragments
    const int nhalf = (jt < 3) ? 2 : 1;  // valid 32-col PV halves

    // stage K (global_load_lds: linear dest, inverse-swizzled source)
#pragma unroll
    for (int is = 0; is < 2; ++is) {
      const int rbase = is * 32 + w * 8;
      const int row = rbase + (lane >> 3);
      const int jg = min(j0 + row, NTOK - 1);
      const int cbs = (lane & 7) ^ (row & 7);
      cp16(Kb + (size_t)jg * 64 + cbs * 8, &Kt[rbase * 64]);
    }
    // stage V transposed: lane covers j=lane (all 64), wave covers d-slab [16w,16w+16)
    {
      const int jl = lane;
      const int jg = min(j0 + jl, NTOK - 1);
      const int dc = w * 16;
      const u16* vp = Vb + (size_t)jg * 64 + dc;
      v8u v0 = *(const v8u*)vp, v1 = *(const v8u*)(vp + 8);
#pragma unroll
      for (int e = 0; e < 8; ++e) {
        const int da = dc + e, db = dc + 8 + e;
        Vt[da * 64 + (((jl >> 3) ^ (da & 7)) * 8) + (jl & 7)] = v0[e];
        Vt[db * 64 + (((jl >> 3) ^ (db & 7)) * 8) + (jl & 7)] = v1[e];
      }
    }
    __syncthreads();   // Kt/Vt ready (drains vmcnt + lgkmcnt)

    // QK^T (Q fragments from LDS per k-step)
    f32x4 sacc[4][4];
#pragma unroll
    for (int a = 0; a < 4; ++a)
#pragma unroll
      for (int b = 0; b < 4; ++b) sacc[a][b] = vz;
#pragma unroll
    for (int ks = 0; ks < 2; ++ks) {
      v8bf qk[4];
#pragma unroll
      for (int mf = 0; mf < 4; ++mf) {
        const int row = 64 * w + mf * 16 + li;
        qk[mf] = *(const v8bf*)&Qs[row * 64 + (((ks * 4 + g) ^ (li & 7)) * 8)];
      }
#pragma unroll
      for (int jf = 0; jf < 4; ++jf) if (jf < njf) {
        const int row = jf * 16 + li;
        v8bf kb = *(const v8bf*)&Kt[row * 64 + (((ks * 4 + g) ^ (li & 7)) * 8)];
#pragma unroll
        for (int mf = 0; mf < 4; ++mf)
          sacc[mf][jf] = __builtin_amdgcn_mfma_f32_16x16x32_bf16(qk[mf], kb, sacc[mf][jf], 0, 0, 0);
      }
    }

    // bias + mask
#pragma unroll
    for (int jf = 0; jf < 4; ++jf) if (jf < njf) {
      const int j = j0 + jf * 16 + li;
      const bool jok = j < 196;
      const int jh = (j * 2341) >> 15;
      const int jw = j - jh * 14;
#pragma unroll
      for (int mf = 0; mf < 4; ++mf)
#pragma unroll
        for (int r = 0; r < 4; ++r) {
          const int i = 64 * w + mf * 16 + 4 * g + r;
          float v;
          if (jok && i < 196)
            v = sacc[mf][jf][r] * 0.125f + bf2f(dhw[i * 32 + jh]) + bf2f(dhw[i * 32 + 16 + jw]);
          else v = -1e30f;
          sacc[mf][jf][r] = v;
        }
    }

    // online softmax update
#pragma unroll
    for (int mf = 0; mf < 4; ++mf)
#pragma unroll
      for (int r = 0; r < 4; ++r) {
        float tmx = -1e30f;
#pragma unroll
        for (int jf = 0; jf < 4; ++jf) if (jf < njf) tmx = fmaxf(tmx, sacc[mf][jf][r]);
#pragma unroll
        for (int o = 1; o < 16; o <<= 1) tmx = fmaxf(tmx, __shfl_xor(tmx, o, 16));
        const int idx = mf * 4 + r;
        const float mnew = fmaxf(mrun[idx], tmx);
        const float sf = __expf(mrun[idx] - mnew);
        mrun[idx] = mnew;
        float ls = 0.f;
#pragma unroll
        for (int jf = 0; jf < 4; ++jf) if (jf < njf) {
          const float p = __expf(sacc[mf][jf][r] - mnew);
          sacc[mf][jf][r] = p;
          ls += p;
        }
#pragma unroll
        for (int o = 1; o < 16; o <<= 1) ls += __shfl_xor(ls, o, 16);
        lrun[idx] = lrun[idx] * sf + ls;
#pragma unroll
        for (int nf = 0; nf < 4; ++nf) oacc[mf][nf][r] *= sf;
      }

    // P chunks (64i x 32j per half) -> PV, two halves; own-wave lgkm ordering
#pragma unroll
    for (int half = 0; half < 2; ++half) if (half < nhalf) {
#pragma unroll
      for (int c = 0; c < 2; ++c) {
        const int jf = half * 2 + c;
        const int jloc = c * 16 + li;
#pragma unroll
        for (int mf = 0; mf < 4; ++mf)
#pragma unroll
          for (int r = 0; r < 4; ++r) {
            const int il = mf * 16 + 4 * g + r;
            u16 pv = 0;
            if (jf < njf) pv = f2bf(sacc[mf][jf][r]);
            Pw[il * 32 + (jloc ^ (g << 3))] = pv;
          }
      }
      // PV: O[i][d] += P[i][j-half] * V[j-half][d]   (K = 32 -> one MFMA per (mf,nf))
      v8bf pa[4];
#pragma unroll
      for (int mf = 0; mf < 4; ++mf) {
        const int row = mf * 16 + li;
        pa[mf] = *(const v8bf*)&Pw[row * 32 + ((g ^ ((li >> 2) & 3)) * 8)];
      }
#pragma unroll
      for (int nf = 0; nf < 4; ++nf) {
        const int d = nf * 16 + li;
        v8bf vb = *(const v8bf*)&Vt[d * 64 + (((half * 4 + g) ^ (li & 7)) * 8)];
#pragma unroll
        for (int mf = 0; mf < 4; ++mf)
          oacc[mf][nf] = __builtin_amdgcn_mfma_f32_16x16x32_bf16(pa[mf], vb, oacc[mf][nf], 0, 0, 0);
      }
    }
    __syncthreads();   // everyone done with Kt/Vt before next tile's staging
  }

  // ---- epilogue: per d-half, transpose through own chunk, 16B stores ----
  float rinv[16];
#pragma unroll
  for (int a = 0; a < 16; ++a) rinv[a] = 1.0f / lrun[a];
#pragma unroll
  for (int half = 0; half < 2; ++half) {
#pragma unroll
    for (int c = 0; c < 2; ++c) {
      const int nf = half * 2 + c;
      const int dloc = c * 16 + li;
#pragma unroll
      for (int mf = 0; mf < 4; ++mf)
#pragma unroll
        for (int r = 0; r < 4; ++r) {
          const int il = mf * 16 + 4 * g + r;
          Pw[il * 32 + (dloc ^ (g << 3))] = f2bf(oacc[mf][nf][r] * rinv[mf * 4 + r]);
        }
    }
#pragma unroll
    for (int p = 0; p < 4; ++p) {
      const int row = p * 16 + (lane >> 2);
      const int seg = lane & 3;
      const int i = 64 * w + row;
      if (i < 196) {
        const int segp = seg ^ ((row >> 2) & 3);
        v8u val = *(const v8u*)&Pw[row * 32 + segp * 8];
        *(v8u*)(out + (size_t)(win * NTOK + i) * DIMC + h * 64 + half * 32 + seg * 8) = val;
      }
    }
  }
}

extern "C" void kernel_launch(void* const* d_in, const int* in_sizes, int n_in,
                              void* d_out, int out_size, void* d_ws, size_t ws_size,
                              hipStream_t stream) {
  (void)in_sizes; (void)n_in; (void)out_size; (void)ws_size;
  const float* x0     = (const float*)d_in[0];
  const float* an1_w  = (const float*)d_in[1];
  const float* an1_b  = (const float*)d_in[2];
  const float* ad1_W  = (const float*)d_in[3];
  const float* ad1_b  = (const float*)d_in[4];
  const float* ac1_W  = (const float*)d_in[5];
  const float* ac1_b  = (const float*)d_in[6];
  const float* au1_W  = (const float*)d_in[7];
  const float* au1_b  = (const float*)d_in[8];
  const float* an2_w  = (const float*)d_in[9];
  const float* an2_b  = (const float*)d_in[10];
  const float* ad2_W  = (const float*)d_in[11];
  const float* ad2_b  = (const float*)d_in[12];
  const float* ac2_W  = (const float*)d_in[13];
  const float* ac2_b  = (const float*)d_in[14];
  const float* au2_W  = (const float*)d_in[15];
  const float* au2_b  = (const float*)d_in[16];
  const float* n1_w   = (const float*)d_in[17];
  const float* n1_b   = (const float*)d_in[18];
  const float* qkv_W  = (const float*)d_in[19];
  const float* qkv_b  = (const float*)d_in[20];
  const float* facu_W = (const float*)d_in[21];
  const float* facv_W = (const float*)d_in[22];
  const float* qfac_W = (const float*)d_in[23];
  const float* vfac_W = (const float*)d_in[24];
  const float* rel_h  = (const float*)d_in[25];
  const float* rel_w  = (const float*)d_in[26];
  const float* proj_W = (const float*)d_in[27];
  const float* proj_b = (const float*)d_in[28];
  const float* n2_w   = (const float*)d_in[29];
  const float* n2_b   = (const float*)d_in[30];
  const float* mlp_W1 = (const float*)d_in[31];
  const float* mlp_b1 = (const float*)d_in[32];
  const float* mlp_W2 = (const float*)d_in[33];
  const float* mlp_b2 = (const float*)d_in[34];

  char* ws = (char*)d_ws;
  size_t off = 0;
  auto alloc = [&](size_t bytes) -> void* {
    void* p = (void*)(ws + off);
    off += (bytes + 255) & ~(size_t)255;
    return p;
  };
  u16*  bufA  = (u16*)alloc((size_t)MS * 3072 * 2);      // qkvR bf16 / mlp hidden bf16
  u16*  bufB  = (u16*)alloc((size_t)MWP * DIMC * 2);     // LN/window tokens + attn out, bf16
  float* bufX = (float*)alloc((size_t)MS * DIMC * 4);    // residual stream f32
  u16*  bufD  = (u16*)alloc((size_t)MS * ACCH * 2);      // adapter down out
  u16*  bufE  = (u16*)alloc((size_t)MS * ACCH * 2);      // adapter conv+gelu out
  u16*  Wcomb = (u16*)alloc((size_t)2304 * 768 * 2);
  u16*  Wproj = (u16*)alloc((size_t)768 * 768 * 2);
  u16*  Wm1   = (u16*)alloc((size_t)3072 * 768 * 2);
  u16*  Wm2   = (u16*)alloc((size_t)768 * 3072 * 2);
  u16*  Wad1  = (u16*)alloc((size_t)256 * 768 * 2);
  u16*  Wau1  = (u16*)alloc((size_t)768 * 192 * 2);
  u16*  Wcv1  = (u16*)alloc((size_t)256 * 5184 * 2);
  u16*  Wad2  = (u16*)alloc((size_t)256 * 768 * 2);
  u16*  Wau2  = (u16*)alloc((size_t)768 * 192 * 2);
  u16*  Wcv2  = (u16*)alloc((size_t)256 * 5184 * 2);
  float* Uq   = (float*)alloc(768 * 32 * 4);
  float* Uv   = (float*)alloc(768 * 32 * 4);
  u16*  zrow  = (u16*)alloc(256);

  // ---- weight prep (every launch; deterministic) ----
  k_zero16<<<1, 256, 0, stream>>>(zrow, 128);
  k_compute_U<<<192, 256, 0, stream>>>(facu_W, qfac_W, vfac_W, Uq, Uv);
  k_build_wcomb<<<(2304 * 768 + 255) / 256, 256, 0, stream>>>(qkv_W, Uq, Uv, facv_W, Wcomb);
  k_cast_pad<<<(768 * 768 + 255) / 256, 256, 0, stream>>>(proj_W, Wproj, 768, 768, 768);
  k_cast_pad<<<(3072 * 768 + 255) / 256, 256, 0, stream>>>(mlp_W1, Wm1, 3072, 768, 3072);
  k_cast_pad<<<(768 * 3072 + 255) / 256, 256, 0, stream>>>(mlp_W2, Wm2, 768, 3072, 768);
  k_cast_pad<<<(256 * 768 + 255) / 256, 256, 0, stream>>>(ad1_W, Wad1, 192, 768, 256);
  k_cast_pad<<<(768 * 192 + 255) / 256, 256, 0, stream>>>(au1_W, Wau1, 768, 192, 768);
  k_cast_pad<<<(256 * 768 + 255) / 256, 256, 0, stream>>>(ad2_W, Wad2, 192, 768, 256);
  k_cast_pad<<<(768 * 192 + 255) / 256, 256, 0, stream>>>(au2_W, Wau2, 768, 192, 768);
  k_conv_repack<<<(256 * 5184 + 255) / 256, 256, 0, stream>>>(ac1_W, Wcv1);
  k_conv_repack<<<(256 * 5184 + 255) / 256, 256, 0, stream>>>(ac2_W, Wcv2);

  // ---- adapter 1: x1 = x0 + up(gelu(conv(down(LN(x0))))) ----
  ln_k<false><<<MS, 256, 0, stream>>>(x0, an1_w, an1_b, bufB);
  gemm_bt<1, false><<<dim3(2, 160), 256, 0, stream>>>(bufB, Wad1, ad1_b, nullptr, nullptr, bufD, MS, 192, 768, nullptr);
  gemm_bt<2, true><<<dim3(2, 160), 256, 0, stream>>>(bufD, Wcv1, ac1_b, nullptr, nullptr, bufE, MS, 192, 5184, zrow);
  gemm_bt<3, false><<<dim3(6, 160), 256, 0, stream>>>(bufE, Wau1, au1_b, x0, bufX, nullptr, MS, 768, 192, nullptr);

  // ---- windowed attention ----
  ln_k<true><<<MWP, 256, 0, stream>>>(bufX, n1_w, n1_b, bufB);
  gemm_bt<4, false><<<dim3(18, 192), 256, 0, stream>>>(bufB, Wcomb, qkv_b, nullptr, nullptr, bufA, MW, 2304, 768, nullptr);
  attn_k<<<125 * HEADS, 256, 0, stream>>>(bufA, rel_h, rel_w, bufB);
  gemm_bt<5, false><<<dim3(6, 192), 256, 0, stream>>>(bufB, Wproj, proj_b, bufX, bufX, nullptr, MW, 768, 768, nullptr);

  // ---- adapter 2 ----
  ln_k<false><<<MS, 256, 0, stream>>>(bufX, an2_w, an2_b, bufB);
  gemm_bt<1, false><<<dim3(2, 160), 256, 0, stream>>>(bufB, Wad2, ad2_b, nullptr, nullptr, bufD, MS, 192, 768, nullptr);
  gemm_bt<2, true><<<dim3(2, 160), 256, 0, stream>>>(bufD, Wcv2, ac2_b, nullptr, nullptr, bufE, MS, 192, 5184, zrow);
  gemm_bt<3, false><<<dim3(6, 160), 256, 0, stream>>>(bufE, Wau2, au2_b, bufX, bufX, nullptr, MS, 768, 192, nullptr);

  // ---- MLP ----
  ln_k<false><<<MS, 256, 0, stream>>>(bufX, n2_w, n2_b, bufB);
  gemm_bt<2, false><<<dim3(24, 160), 256, 0, stream>>>(bufB, Wm1, mlp_b1, nullptr, nullptr, bufA, MS, 3072, 768, nullptr);
  gemm_bt<3, false><<<dim3(6, 160), 256, 0, stream>>>(bufA, Wm2, mlp_b2, bufX, (float*)d_out, nullptr, MS, 768, 3072, nullptr);
}